// Round 11
// baseline (1522.176 us; speedup 1.0000x reference)
//
#include <hip/hip_runtime.h>
#include <stdint.h>

// ===== LinearQ4_0: out[8192,11008] = x[8192,4096] * W^T, W q4_0 packed =====
#define IN_F   4096
#define OUT_F  11008
#define M_ROWS 8192
#define BM 256
#define BN 256
#define BK 64
#define NTILE_K (IN_F / BK)   // 64 K-tiles, 2 per iteration -> 32 iters

typedef __attribute__((ext_vector_type(4))) float  f32x4;
typedef __attribute__((ext_vector_type(4))) int    int4v;
typedef __attribute__((ext_vector_type(8))) unsigned short ushort8;
typedef __bf16 bf16x8 __attribute__((ext_vector_type(8)));

__device__ __forceinline__ unsigned short f2bf(float f) {
  unsigned int u = __builtin_bit_cast(unsigned int, f);
  u += 0x7fffu + ((u >> 16) & 1u);
  return (unsigned short)(u >> 16);
}

// ---- kernel 1: repack q4_0 int32-expanded bytes -> tight int4 pairs wq[OUT_F][IN_F/2] ----
// wq byte kb of row o: low nibble = q(o,2kb), high nibble = q(o,2kb+1).
__global__ __launch_bounds__(256) void pack_w(const int* __restrict__ w,
                                              unsigned int* __restrict__ wq) {
  const int totald = OUT_F * (IN_F / 8);   // one u32 = 8 nibbles = 8 k-values
  for (int d = blockIdx.x * blockDim.x + threadIdx.x; d < totald;
       d += gridDim.x * blockDim.x) {
    const int o   = d >> 9;                // 512 dwords per row
    const int k0  = (d & 511) * 8;
    const int n   = o * 64 + (k0 >> 6);    // group index
    const int p   = n >> 1;
    const int nib = n & 1;
    const int j0  = k0 & 63;
    const int* src = w + p * 64 + j0;
    const int4v b0 = __builtin_nontemporal_load(reinterpret_cast<const int4v*>(src));
    const int4v b1 = __builtin_nontemporal_load(reinterpret_cast<const int4v*>(src + 4));
    unsigned int acc = 0;
#pragma unroll
    for (int i = 0; i < 8; ++i) {
      const int b = (i < 4) ? b0[i] : b1[i - 4];
      const int q = nib ? ((b << 28) >> 28) : (b >> 4);
      acc |= ((unsigned int)(q & 0xF)) << (4 * i);
    }
    wq[d] = acc;
  }
}

// ---- kernel 1b: transpose scales fp32 s[OUT_F][64] -> fp16 st[64][OUT_F] ----
__global__ __launch_bounds__(256) void scale_t(const float* __restrict__ s,
                                               unsigned short* __restrict__ st) {
  const int o = blockIdx.x * 256 + threadIdx.x;   // gridDim.x = 43
  const int g = blockIdx.y;                        // 64
  if (o < OUT_F) {
    _Float16 h = (_Float16)s[o * 64 + g];
    st[g * OUT_F + o] = __builtin_bit_cast(unsigned short, h);
  }
}

// ---- kernel 2: x fp32 -> bf16 (nt loads: read-once) ----
__global__ __launch_bounds__(256) void cvt_x(const float* __restrict__ x,
                                             unsigned short* __restrict__ xb) {
  const int total8 = (M_ROWS * IN_F) / 8;
  for (int t = blockIdx.x * blockDim.x + threadIdx.x; t < total8;
       t += gridDim.x * blockDim.x) {
    const f32x4 a0 = __builtin_nontemporal_load(reinterpret_cast<const f32x4*>(x + t * 8));
    const f32x4 a1 = __builtin_nontemporal_load(reinterpret_cast<const f32x4*>(x + t * 8 + 4));
    ushort8 r;
#pragma unroll
    for (int e = 0; e < 4; ++e) {
      r[e]     = f2bf(a0[e]);
      r[4 + e] = f2bf(a1[e]);
    }
    *reinterpret_cast<ushort8*>(xb + t * 8) = r;
  }
}

// ---- async global -> LDS, 16 B per lane ----
__device__ __forceinline__ void gld16(const void* g, void* l) {
  __builtin_amdgcn_global_load_lds(
      (const __attribute__((address_space(1))) unsigned int*)(uintptr_t)g,
      (__attribute__((address_space(3))) unsigned int*)(unsigned int)(uintptr_t)l,
      16, 0, 0);
}

#define BAR() do { asm volatile("" ::: "memory"); __builtin_amdgcn_s_barrier(); \
                   asm volatile("" ::: "memory"); } while (0)

// ---- kernel 3: 8-phase, 1 bar/phase, one-phase-ahead reads, PACKED-int4 B. ----
// LDS (ushorts): A buf b at b*16384 ([kh][256][32] bf16, swizzled);
//   BQ buf b at 32768 + b*4096 (256 rows x 32 B packed nibbles, linear);
//   SL at 40960: fp16 scales [64 groups][256 cols].  Total 114688 B.
// Loads/iter = 10: P1{bq1,a11,a11} P3{a00,a00} P4{bq0} P5{a01,a01} P7{a10,a10}.
// Waits: vmcnt(5)@P1, (4)@P3, (5)@P5, (4)@P7 (pre-BAR). FIFO sim (steady):
//  enter P1 [a01,a01,a10,a10] -> P1 +3 w(5) drains a01x2 -> P3 +2 w(4) drains
//  a10x2,bq1 -> P4 +1 -> P5 +2 w(5) drains a11x2 -> P7 +2 w(4) drains a00x2,bq0
//  -> back to [a01,a01,a10,a10].  Every RD >=1 barrier after its drain.
// WAR gaps match the R5-R9-proven pattern (stage >= 1 barrier + consuming-MFMA
// after the region's last phase-top read; BQ stages have 2+ full barriers).
__global__ __launch_bounds__(512, 2) void gemm_bt(const unsigned short* __restrict__ A,
                                                  const unsigned char* __restrict__ WQ,
                                                  const unsigned short* __restrict__ ST,
                                                  float* __restrict__ C) {
  __shared__ __align__(16) unsigned short lds[57344];  // 112 KB

  const int NT  = OUT_F / BN;              // 43
  const int nwg = (M_ROWS / BM) * NT;      // 1376, %8==0
  const int cpx = nwg >> 3;
  const int bid = blockIdx.x;
  const int swz = (bid & 7) * cpx + (bid >> 3);
  const int mt  = swz / NT;
  const int nt  = swz - mt * NT;
  const int n0  = nt * BN;

  const int tid  = threadIdx.x;
  const int lane = tid & 63;
  const int wid  = tid >> 6;      // 8 waves: 2 (M) x 4 (N)
  const int wr   = wid >> 2;
  const int wc   = wid & 3;

  // ---- A staging: thread t -> row t>>2, phys chunk t&3; source chunk = pc ^ ((row>>1)&3) ----
  const int r_st = tid >> 2;
  const int lc   = (tid & 3) ^ ((tid >> 3) & 3);
  const unsigned short* gA = A + (size_t)(mt * BM + r_st) * IN_F + lc * 8;
  unsigned short* ldsw = lds + tid * 8;

#define STAGE_A(b, h, kk) do {                                              \
    unsigned short* d_ = ldsw + (b) * 16384 + (h) * 8192;                   \
    const unsigned short* s_ = gA + (kk) + (h) * 32;                        \
    gld16(s_, d_); gld16(s_ + (size_t)128 * IN_F, d_ + 4096);               \
  } while (0)

  // ---- BQ staging: thread t -> row t>>1, 16B chunk t&1 (linear both sides) ----
  const unsigned char* gBQ = WQ + (size_t)(n0 + (tid >> 1)) * (IN_F / 2) + (tid & 1) * 16;
#define STAGE_BQ(b, tk) \
    gld16(gBQ + (tk) * 32, lds + 32768 + (b) * 4096 + tid * 8)

  // ---- scale staging (prologue): 4 calls, 2048 slots of 16 B ----
#define STAGE_SL(c) do {                                                    \
    const int sl_ = (c) * 512 + tid;                                        \
    gld16(ST + (size_t)(sl_ >> 5) * OUT_F + n0 + (sl_ & 31) * 8,            \
          lds + 40960 + sl_ * 8);                                           \
  } while (0)

  // ---- fragment reads ----
  const int fr   = lane & 15;
  const int kq   = lane >> 4;
  const int coff = (kq ^ ((fr >> 1) & 3)) * 8;

  bf16x8 aS0[4], aS1[4], bS0[4], bS1[4];
#define RD_A(dst, b, h, mq) do {                                            \
    const unsigned short* p_ = lds + (b) * 16384 + (h) * 8192 + coff;       \
    _Pragma("unroll") for (int mm = 0; mm < 4; ++mm)                        \
      dst[mm] = *reinterpret_cast<const bf16x8*>(                           \
          p_ + (size_t)(wr * 128 + (mq) * 64 + mm * 16 + fr) * 32);         \
  } while (0)

  // packed-B read + in-register dequant: frag = 8 consecutive k of row o
#define RD_B(dst, b, h, g) do {                                             \
    _Pragma("unroll") for (int nn = 0; nn < 4; ++nn) {                      \
      const int o_ = wc * 64 + nn * 16 + fr;                                \
      const unsigned int w4 = *reinterpret_cast<const unsigned int*>(       \
          lds + 32768 + (b) * 4096 + o_ * 16 + ((h) * 4 + kq) * 2);         \
      const float sc_ = (float)(*reinterpret_cast<const _Float16*>(         \
          lds + 40960 + (g) * 256 + o_));                                   \
      _Pragma("unroll") for (int i = 0; i < 8; ++i) {                       \
        const int v_ = ((int)(w4 << (28 - 4 * i))) >> 28;                   \
        dst[nn][i] = (__bf16)((float)v_ * sc_);                             \
      }                                                                     \
    }                                                                       \
  } while (0)

  f32x4 acc[8][4] = {};
#define MFMA16(mq, aset, bset) do {                                         \
    __builtin_amdgcn_s_setprio(1);                                          \
    _Pragma("unroll") for (int mm = 0; mm < 4; ++mm)                        \
      _Pragma("unroll") for (int nn = 0; nn < 4; ++nn)                      \
        acc[(mq)*4+mm][nn] = __builtin_amdgcn_mfma_f32_16x16x32_bf16(       \
            aset[mm], bset[nn], acc[(mq)*4+mm][nn], 0, 0, 0);               \
    __builtin_amdgcn_s_setprio(0);                                          \
  } while (0)

#define VW(n) asm volatile("s_waitcnt vmcnt(" #n ")" ::: "memory")

  // ---- prologue: [scales x4, bq0(t0), a00 x2] must land; in-flight [a01x2, a10x2] ----
  STAGE_SL(0); STAGE_SL(1); STAGE_SL(2); STAGE_SL(3);
  STAGE_BQ(0, 0);
  STAGE_A(0, 0, 0);
  STAGE_A(0, 1, 0);        // a01 (tile0 kh1)
  STAGE_A(1, 0, BK);       // a10 (tile1 kh0)
  VW(4);
  BAR();
  RD_A(aS0, 0, 0, 0); RD_B(bS0, 0, 0, 0);   // operands for MFMA(P1)

  for (int it = 0; it < NTILE_K / 2; ++it) {
    const int t1i = 2 * it + 1;
    const int t2i = (2 * it + 2) & (NTILE_K - 1);
    const int t3i = (2 * it + 3) & (NTILE_K - 1);
    const int kt1 = t1i * BK, kt2 = t2i * BK, kt3 = t3i * BK;

    // P1: stage bq1,a11 ; RD->P2 A(0,0,m4-7) ; MFMA Ta kh0 m0-3
    STAGE_BQ(1, t1i); STAGE_A(1, 1, kt1);
    RD_A(aS1, 0, 0, 1); VW(5);
    BAR(); MFMA16(0, aS0, bS0);
    // P2: RD->P3 A(0,1)+B(0,kh1) ; MFMA Ta kh0 m4-7
    RD_A(aS0, 0, 1, 0); RD_B(bS1, 0, 1, 2 * it);
    BAR(); MFMA16(1, aS1, bS0);
    // P3: stage a00' ; RD->P4 A(0,1,m4-7) ; MFMA Ta kh1 m0-3
    STAGE_A(0, 0, kt2);
    RD_A(aS1, 0, 1, 1); VW(4);
    BAR(); MFMA16(0, aS0, bS1);
    // P4: stage bq0' ; RD->P5 A(1,0)+B(1,kh0) ; MFMA Ta kh1 m4-7
    STAGE_BQ(0, t2i);
    RD_A(aS0, 1, 0, 0); RD_B(bS0, 1, 0, t1i);
    BAR(); MFMA16(1, aS1, bS1);
    // P5: stage a01' ; RD->P6 A(1,0,m4-7) ; MFMA Tb kh0 m0-3
    STAGE_A(0, 1, kt2);
    RD_A(aS1, 1, 0, 1); VW(5);
    BAR(); MFMA16(0, aS0, bS0);
    // P6: RD->P7 A(1,1)+B(1,kh1) ; MFMA Tb kh0 m4-7
    RD_A(aS0, 1, 1, 0); RD_B(bS1, 1, 1, t1i);
    BAR(); MFMA16(1, aS1, bS0);
    // P7: stage a10' ; RD->P8 A(1,1,m4-7) ; MFMA Tb kh1 m0-3
    STAGE_A(1, 0, kt3);
    RD_A(aS1, 1, 1, 1); VW(4);
    BAR(); MFMA16(0, aS0, bS1);
    // P8: RD->next-P1 A(0,0)'+B(0,kh0)' ; MFMA Tb kh1 m4-7
    RD_A(aS0, 0, 0, 0); RD_B(bS0, 0, 0, t2i);
    BAR(); MFMA16(1, aS1, bS1);
  }

  // ---- epilogue ----
  const int col  = n0 + wc * 64 + fr;
  const int row0 = mt * BM + wr * 128 + (lane >> 4) * 4;
#pragma unroll
  for (int m = 0; m < 8; ++m) {
#pragma unroll
    for (int n = 0; n < 4; ++n) {
      float* cp = C + (size_t)(row0 + m * 16) * OUT_F + (col + n * 16);
#pragma unroll
      for (int r = 0; r < 4; ++r) cp[(size_t)r * OUT_F] = acc[m][n][r];
    }
  }
}

extern "C" void kernel_launch(void* const* d_in, const int* in_sizes, int n_in,
                              void* d_out, int out_size, void* d_ws, size_t ws_size,
                              hipStream_t stream) {
  const float* x = (const float*)d_in[0];
  const int*   w = (const int*)d_in[1];
  const float* s = (const float*)d_in[2];
  float*     out = (float*)d_out;

  // d_ws layout: xb bf16 [8192][4096] (64 MB) | wq int4-packed (21.5 MB) | st fp16 (1.35 MB)
  unsigned short* xb = (unsigned short*)d_ws;
  unsigned char*  wq = (unsigned char*)d_ws + (size_t)M_ROWS * IN_F * 2;
  unsigned short* st = (unsigned short*)(wq + (size_t)OUT_F * (IN_F / 2));

  pack_w<<<dim3(2048), dim3(256), 0, stream>>>(w, (unsigned int*)wq);
  scale_t<<<dim3(43, 64), dim3(256), 0, stream>>>(s, st);
  cvt_x<<<dim3(2048), dim3(256), 0, stream>>>(x, xb);
  gemm_bt<<<dim3((M_ROWS / BM) * (OUT_F / BN)), dim3(512), 0, stream>>>(xb, wq, st, out);
}

// Round 13
// 855.591 us; speedup vs baseline: 1.7791x; 1.7791x over previous
//
#include <hip/hip_runtime.h>
#include <stdint.h>

// ===== LinearQ4_0: out[8192,11008] = x[8192,4096] * W^T, W q4_0 packed =====
#define IN_F   4096
#define OUT_F  11008
#define M_ROWS 8192
#define BM 256
#define BN 256
#define BK 64
#define NTILE_K (IN_F / BK)   // 64 K-tiles (= 64 scale groups), 2 per iteration

typedef __attribute__((ext_vector_type(4))) float  f32x4;
typedef __attribute__((ext_vector_type(4))) int    int4v;
typedef __attribute__((ext_vector_type(4))) unsigned int uint4v;
typedef __attribute__((ext_vector_type(8))) unsigned short ushort8;
typedef _Float16 f16x8 __attribute__((ext_vector_type(8)));
typedef _Float16 f16x2 __attribute__((ext_vector_type(2)));

// ---- kernel 1: repack q4_0 -> BIASED nibbles wq[OUT_F][IN_F/8] u32 ----
// u32 c of row o: nibble j = q(o, 8c+j) + 8  (in [1,15]).
__global__ __launch_bounds__(256) void pack_w(const int* __restrict__ w,
                                              unsigned int* __restrict__ wq) {
  const int totald = OUT_F * (IN_F / 8);
  for (int d = blockIdx.x * blockDim.x + threadIdx.x; d < totald;
       d += gridDim.x * blockDim.x) {
    const int o   = d >> 9;                // 512 u32 per row
    const int k0  = (d & 511) * 8;
    const int n   = o * 64 + (k0 >> 6);    // group index
    const int p   = n >> 1;
    const int nib = n & 1;
    const int j0  = k0 & 63;
    const int* src = w + p * 64 + j0;
    const int4v b0 = __builtin_nontemporal_load(reinterpret_cast<const int4v*>(src));
    const int4v b1 = __builtin_nontemporal_load(reinterpret_cast<const int4v*>(src + 4));
    unsigned int acc = 0;
#pragma unroll
    for (int i = 0; i < 8; ++i) {
      const int b = (i < 4) ? b0[i] : b1[i - 4];
      const int q = nib ? ((b << 28) >> 28) : (b >> 4);
      acc |= ((unsigned int)((q + 8) & 0xF)) << (4 * i);
    }
    wq[d] = acc;
  }
}

// ---- kernel 1b: transpose scales fp32 s[OUT_F][64] -> fp16 st[64][OUT_F] ----
__global__ __launch_bounds__(256) void scale_t(const float* __restrict__ s,
                                               unsigned short* __restrict__ st) {
  const int o = blockIdx.x * 256 + threadIdx.x;
  const int g = blockIdx.y;
  if (o < OUT_F) {
    _Float16 h = (_Float16)s[o * 64 + g];
    st[g * OUT_F + o] = __builtin_bit_cast(unsigned short, h);
  }
}

// ---- kernel 2: x fp32 -> fp16 (exact round-trip; input was fp16) ----
__global__ __launch_bounds__(256) void cvt_x(const float* __restrict__ x,
                                             unsigned short* __restrict__ xb) {
  const int total8 = (M_ROWS * IN_F) / 8;
  for (int t = blockIdx.x * blockDim.x + threadIdx.x; t < total8;
       t += gridDim.x * blockDim.x) {
    const f32x4 a0 = __builtin_nontemporal_load(reinterpret_cast<const f32x4*>(x + t * 8));
    const f32x4 a1 = __builtin_nontemporal_load(reinterpret_cast<const f32x4*>(x + t * 8 + 4));
    ushort8 r;
#pragma unroll
    for (int e = 0; e < 4; ++e) {
      r[e]     = __builtin_bit_cast(unsigned short, (_Float16)a0[e]);
      r[4 + e] = __builtin_bit_cast(unsigned short, (_Float16)a1[e]);
    }
    *reinterpret_cast<ushort8*>(xb + t * 8) = r;
  }
}

// ---- async global -> LDS, 16 B per lane ----
__device__ __forceinline__ void gld16(const void* g, void* l) {
  __builtin_amdgcn_global_load_lds(
      (const __attribute__((address_space(1))) unsigned int*)(uintptr_t)g,
      (__attribute__((address_space(3))) unsigned int*)(unsigned int)(uintptr_t)l,
      16, 0, 0);
}

#define BAR() do { asm volatile("" ::: "memory"); __builtin_amdgcn_s_barrier(); \
                   asm volatile("" ::: "memory"); } while (0)

// ---- kernel 3: R8 8-phase/1-barrier schedule, fp16, PACKED-int4 B. ----
// LDS (ushorts): A buf b at b*16384 ([kh][256][32] f16, swizzled chunk^=((row>>1)&3));
//   BQ buf b at 32768 + b*4096 (256 rows x 32 B biased nibbles, linear);
//   SL at 40960: fp16 scales [64 groups][256 cols] (staged once). 112 KB total.
// Loads/iter = 10: P1:A11(2) P2:BQ1(1) P3:A00'(2) P4:BQ0'(1) P5:A01'(2) P7:A10'(2).
// Waits (pre-BAR): P2 vmcnt(5), P4 vmcnt(3), P8 vmcnt(4).  FIFO-sim verified:
//   prologue exit = [A01 x2, A10 x2] outstanding = steady P1-entry state;
//   P2-wait drains A01 (read P3,P4); P4-wait drains A10,A11,BQ1 (read P5-P8);
//   P8-wait drains A00',BQ0' (read next P1,P2). Every RD >=1 barrier after drain.
// WAR: every stage target's last phase-top reader completes >=1 barrier earlier
//   (P1:A11<-prev P8, P2:BQ1<-prev P7, P3:A00<-P2, P4:BQ0<-P3, P5:A01<-P4, P7:A10<-P6).
// Dequant (R12 bug fixed): nibble n=q+8 -> fp16 (0x6400|n) = 1024+n exactly;
//   fma(v, s, -1024s) = n*s (c1 = -1024s EXACT, forced fma), then + (-8s) (EXACT)
//   = q*s. Two roundings, random-sign; NO 0.5s group-coherent bias (R12's fail).
__global__ __launch_bounds__(512, 2) void gemm_bt(const unsigned short* __restrict__ A,
                                                  const unsigned char* __restrict__ WQ,
                                                  const unsigned short* __restrict__ ST,
                                                  float* __restrict__ C) {
  __shared__ __align__(16) unsigned short lds[57344];  // 112 KB

  const int NT  = OUT_F / BN;              // 43
  const int nwg = (M_ROWS / BM) * NT;      // 1376, %8==0
  const int cpx = nwg >> 3;
  const int bid = blockIdx.x;
  const int swz = (bid & 7) * cpx + (bid >> 3);
  const int mt  = swz / NT;
  const int nt  = swz - mt * NT;
  const int n0  = nt * BN;

  const int tid  = threadIdx.x;
  const int lane = tid & 63;
  const int wid  = tid >> 6;      // 8 waves: 2 (M) x 4 (N)
  const int wr   = wid >> 2;
  const int wc   = wid & 3;

  // ---- A staging: thread t -> row t>>2, phys chunk t&3; source chunk ^= ((row>>1)&3) ----
  const int r_st = tid >> 2;
  const int lc   = (tid & 3) ^ ((tid >> 3) & 3);
  const unsigned short* gA = A + (size_t)(mt * BM + r_st) * IN_F + lc * 8;
  unsigned short* ldsw = lds + tid * 8;

#define STAGE_A(b, h, kk) do {                                              \
    unsigned short* d_ = ldsw + (b) * 16384 + (h) * 8192;                   \
    const unsigned short* s_ = gA + (kk) + (h) * 32;                        \
    gld16(s_, d_); gld16(s_ + (size_t)128 * IN_F, d_ + 4096);               \
  } while (0)

  // ---- BQ staging: thread t -> row t>>1, 16B chunk t&1; 1 gld16 = whole 8KB tile ----
  const unsigned char* gBQ = WQ + (size_t)(n0 + (tid >> 1)) * (IN_F / 2) + (tid & 1) * 16;
#define STAGE_BQ(b, tk) \
    gld16(gBQ + (size_t)(tk) * 32, lds + 32768 + (b) * 4096 + tid * 8)

  // ---- SL staging (prologue only): [64][256] fp16 = 32 KB = 4 sweeps ----
#define STAGE_SL(c) do {                                                    \
    const int sl_ = (c) * 512 + tid;                                        \
    gld16(ST + (size_t)(sl_ >> 5) * OUT_F + n0 + (sl_ & 31) * 8,            \
          lds + 40960 + sl_ * 8);                                           \
  } while (0)

  // ---- fragment reads ----
  const int fr   = lane & 15;
  const int kq   = lane >> 4;
  const int coff = (kq ^ ((fr >> 1) & 3)) * 8;

  f16x8 afr[4], bfr[4];
#define RD_A(b, h, mq) do {                                                 \
    const unsigned short* p_ = lds + (b) * 16384 + (h) * 8192 + coff;       \
    _Pragma("unroll") for (int mm = 0; mm < 4; ++mm)                        \
      afr[mm] = *reinterpret_cast<const f16x8*>(                            \
          p_ + (size_t)(wr * 128 + (mq) * 64 + mm * 16 + fr) * 32);         \
  } while (0)

  // packed-B dequant: frag = 8 consecutive k of row o; all static-indexed;
  // exact constants c1=-1024s, c8=-8s; forced fma (no contraction gamble).
#define DEQ_B(bbuf, kh, g) do {                                             \
    _Pragma("unroll") for (int nn = 0; nn < 4; ++nn) {                      \
      const int o_ = wc * 64 + nn * 16 + fr;                                \
      const unsigned int w4 = *reinterpret_cast<const unsigned int*>(       \
          lds + 32768 + (bbuf) * 4096 + o_ * 16 + (kh) * 8 + kq * 2);       \
      const _Float16 s_  = *reinterpret_cast<const _Float16*>(              \
          lds + 40960 + (g) * 256 + o_);                                    \
      const _Float16 c1_ = s_ * (_Float16)(-1024.0f);  /* exact */          \
      const _Float16 c8_ = s_ * (_Float16)(-8.0f);     /* exact */          \
      f16x2 s2; s2[0] = s_;  s2[1] = s_;                                    \
      f16x2 c1; c1[0] = c1_; c1[1] = c1_;                                   \
      f16x2 c8; c8[0] = c8_; c8[1] = c8_;                                   \
      uint4v rr;                                                            \
      _Pragma("unroll") for (int j = 0; j < 4; ++j) {                       \
        const unsigned int t_ = w4 >> (8 * j);                              \
        const unsigned int m_ = (t_ & 0xFu) | ((t_ << 12) & 0xF0000u)       \
                              | 0x64006400u;                                \
        f16x2 v_ = __builtin_bit_cast(f16x2, m_);                           \
        v_ = __builtin_elementwise_fma(v_, s2, c1);   /* = n*s, 1 rnd */    \
        v_ = v_ + c8;                                  /* = q*s */          \
        rr[j] = __builtin_bit_cast(unsigned int, v_);                       \
      }                                                                     \
      bfr[nn] = __builtin_bit_cast(f16x8, rr);                              \
    }                                                                       \
  } while (0)

  f32x4 acc[8][4] = {};
#define MFMA16(mq) do {                                                     \
    __builtin_amdgcn_s_setprio(1);                                          \
    _Pragma("unroll") for (int mm = 0; mm < 4; ++mm)                        \
      _Pragma("unroll") for (int nn = 0; nn < 4; ++nn)                      \
        acc[(mq)*4+mm][nn] = __builtin_amdgcn_mfma_f32_16x16x32_f16(        \
            afr[mm], bfr[nn], acc[(mq)*4+mm][nn], 0, 0, 0);                 \
    __builtin_amdgcn_s_setprio(0);                                          \
  } while (0)

#define VW(n) asm volatile("s_waitcnt vmcnt(" #n ")" ::: "memory")

  // ---- prologue: 11 loads; vmcnt(4) drains SL x4 + A00 x2 + BQ0;
  //      in-flight [A01 x2, A10 x2] = steady P1-entry state ----
  STAGE_SL(0); STAGE_SL(1); STAGE_SL(2); STAGE_SL(3);
  STAGE_A(0, 0, 0);
  STAGE_BQ(0, 0);
  STAGE_A(0, 1, 0);
  STAGE_A(1, 0, BK);
  VW(4);
  BAR();

  for (int it = 0; it < NTILE_K / 2; ++it) {
    const int ta  = 2 * it;
    const int tb  = 2 * it + 1;
    const int tna = (2 * it + 2) & (NTILE_K - 1);
    const int tnb = (2 * it + 3) & (NTILE_K - 1);

    // P1: stage A11(tb) ; deq B(0,kh0,g=ta) + RD A(0,0,m0-3) ; MFMA
    STAGE_A(1, 1, tb * BK);
    DEQ_B(0, 0, ta); RD_A(0, 0, 0);
    BAR(); MFMA16(0);
    // P2: stage BQ1(tb) ; RD A(0,0,m4-7) ; wait -> A01'(prev) resident
    STAGE_BQ(1, tb);
    RD_A(0, 0, 1);
    VW(5);
    BAR(); MFMA16(1);
    // P3: stage A00'(tna) ; deq B(0,kh1,ta) + RD A(0,1,m0-3) ; MFMA
    STAGE_A(0, 0, tna * BK);
    DEQ_B(0, 1, ta); RD_A(0, 1, 0);
    BAR(); MFMA16(0);
    // P4: stage BQ0'(tna) ; RD A(0,1,m4-7) ; wait -> A10',A11,BQ1 resident
    STAGE_BQ(0, tna);
    RD_A(0, 1, 1);
    VW(3);
    BAR(); MFMA16(1);
    // P5: stage A01'(tna) ; deq B(1,kh0,tb) + RD A(1,0,m0-3) ; MFMA
    STAGE_A(0, 1, tna * BK);
    DEQ_B(1, 0, tb); RD_A(1, 0, 0);
    BAR(); MFMA16(0);
    // P6: RD A(1,0,m4-7) ; MFMA
    RD_A(1, 0, 1);
    BAR(); MFMA16(1);
    // P7: stage A10'(tnb) ; deq B(1,kh1,tb) + RD A(1,1,m0-3) ; MFMA
    STAGE_A(1, 0, tnb * BK);
    DEQ_B(1, 1, tb); RD_A(1, 1, 0);
    BAR(); MFMA16(0);
    // P8: RD A(1,1,m4-7) ; wait -> A00'',BQ0'' resident for next P1
    RD_A(1, 1, 1);
    VW(4);
    BAR(); MFMA16(1);
  }

  asm volatile("s_waitcnt vmcnt(0)" ::: "memory");  // drain tail stages

  // ---- epilogue: plain stores ----
  const int col  = n0 + wc * 64 + fr;
  const int row0 = mt * BM + wr * 128 + (lane >> 4) * 4;
#pragma unroll
  for (int m = 0; m < 8; ++m) {
#pragma unroll
    for (int n = 0; n < 4; ++n) {
      float* cp = C + (size_t)(row0 + m * 16) * OUT_F + (col + n * 16);
#pragma unroll
      for (int r = 0; r < 4; ++r) cp[(size_t)r * OUT_F] = acc[m][n][r];
    }
  }
}

extern "C" void kernel_launch(void* const* d_in, const int* in_sizes, int n_in,
                              void* d_out, int out_size, void* d_ws, size_t ws_size,
                              hipStream_t stream) {
  const float* x = (const float*)d_in[0];
  const int*   w = (const int*)d_in[1];
  const float* s = (const float*)d_in[2];
  float*     out = (float*)d_out;

  // d_ws: xb f16 [8192][4096] (64 MB) | wq packed u32 (21.5 MB) | st f16 (1.35 MB)
  unsigned short* xb = (unsigned short*)d_ws;
  unsigned char*  wq = (unsigned char*)d_ws + (size_t)M_ROWS * IN_F * 2;
  unsigned short* st = (unsigned short*)(wq + (size_t)OUT_F * (IN_F / 2));

  pack_w<<<dim3(2048), dim3(256), 0, stream>>>(w, (unsigned int*)wq);
  scale_t<<<dim3(43, 64), dim3(256), 0, stream>>>(s, st);
  cvt_x<<<dim3(2048), dim3(256), 0, stream>>>(x, xb);
  gemm_bt<<<dim3((M_ROWS / BM) * (OUT_F / BN)), dim3(512), 0, stream>>>(xb, wq, st, out);
}

// Round 14
// 792.134 us; speedup vs baseline: 1.9216x; 1.0801x over previous
//
#include <hip/hip_runtime.h>
#include <stdint.h>

// ===== LinearQ4_0: out[8192,11008] = x[8192,4096] * W^T, W q4_0 packed =====
#define IN_F   4096
#define OUT_F  11008
#define M_ROWS 8192
#define BM 256
#define BN 256
#define BK 64
#define NTILE_K (IN_F / BK)   // 64 K-tiles (= 64 scale groups), 2 per iteration

typedef __attribute__((ext_vector_type(4))) float  f32x4;
typedef __attribute__((ext_vector_type(4))) int    int4v;
typedef __attribute__((ext_vector_type(4))) unsigned int uint4v;
typedef __attribute__((ext_vector_type(8))) unsigned short ushort8;
typedef _Float16 f16x8 __attribute__((ext_vector_type(8)));
typedef _Float16 f16x2 __attribute__((ext_vector_type(2)));

// ---- kernel 1: repack q4_0 -> INTERLEAVED biased nibbles wq[OUT_F][IN_F/8] u32 ----
// u32 c of row o: elem e (k = 8c+e) -> nibble pos (e>>1) + (e&1)*4, value q+8.
// Then ((w4>>4p) & 0x000F000F) | 0x64006400 yields f16-pair (elem 2p, elem 2p+1).
__global__ __launch_bounds__(256) void pack_w(const int* __restrict__ w,
                                              unsigned int* __restrict__ wq) {
  const int totald = OUT_F * (IN_F / 8);
  for (int d = blockIdx.x * blockDim.x + threadIdx.x; d < totald;
       d += gridDim.x * blockDim.x) {
    const int o   = d >> 9;                // 512 u32 per row
    const int k0  = (d & 511) * 8;
    const int n   = o * 64 + (k0 >> 6);    // group index
    const int p   = n >> 1;
    const int nib = n & 1;
    const int j0  = k0 & 63;
    const int* src = w + p * 64 + j0;
    const int4v b0 = __builtin_nontemporal_load(reinterpret_cast<const int4v*>(src));
    const int4v b1 = __builtin_nontemporal_load(reinterpret_cast<const int4v*>(src + 4));
    unsigned int acc = 0;
#pragma unroll
    for (int i = 0; i < 8; ++i) {
      const int b = (i < 4) ? b0[i] : b1[i - 4];
      const int q = nib ? ((b << 28) >> 28) : (b >> 4);
      const int pos = (i >> 1) + ((i & 1) << 2);
      acc |= ((unsigned int)((q + 8) & 0xF)) << (4 * pos);
    }
    wq[d] = acc;
  }
}

// ---- kernel 1b: transpose scales fp32 s[OUT_F][64] -> fp16 st[64][OUT_F] ----
__global__ __launch_bounds__(256) void scale_t(const float* __restrict__ s,
                                               unsigned short* __restrict__ st) {
  const int o = blockIdx.x * 256 + threadIdx.x;
  const int g = blockIdx.y;
  if (o < OUT_F) {
    _Float16 h = (_Float16)s[o * 64 + g];
    st[g * OUT_F + o] = __builtin_bit_cast(unsigned short, h);
  }
}

// ---- kernel 2: x fp32 -> fp16 (exact round-trip; input was fp16) ----
__global__ __launch_bounds__(256) void cvt_x(const float* __restrict__ x,
                                             unsigned short* __restrict__ xb) {
  const int total8 = (M_ROWS * IN_F) / 8;
  for (int t = blockIdx.x * blockDim.x + threadIdx.x; t < total8;
       t += gridDim.x * blockDim.x) {
    const f32x4 a0 = __builtin_nontemporal_load(reinterpret_cast<const f32x4*>(x + t * 8));
    const f32x4 a1 = __builtin_nontemporal_load(reinterpret_cast<const f32x4*>(x + t * 8 + 4));
    ushort8 r;
#pragma unroll
    for (int e = 0; e < 4; ++e) {
      r[e]     = __builtin_bit_cast(unsigned short, (_Float16)a0[e]);
      r[4 + e] = __builtin_bit_cast(unsigned short, (_Float16)a1[e]);
    }
    *reinterpret_cast<ushort8*>(xb + t * 8) = r;
  }
}

// ---- async global -> LDS, 16 B per lane ----
__device__ __forceinline__ void gld16(const void* g, void* l) {
  __builtin_amdgcn_global_load_lds(
      (const __attribute__((address_space(1))) unsigned int*)(uintptr_t)g,
      (__attribute__((address_space(3))) unsigned int*)(unsigned int)(uintptr_t)l,
      16, 0, 0);
}

#define BAR() do { asm volatile("" ::: "memory"); __builtin_amdgcn_s_barrier(); \
                   asm volatile("" ::: "memory"); } while (0)

// ---- kernel 3: 8-phase, 1 bar/phase, FULL operand ping-pong, packed-int4 B. ----
// Phase k top computes MFMA(k+1)'s operands (afrA/B, bfrA/B alternate) -> dequant
// VALU overlaps the MFMA pipe (no WAR on operand regs).
// LDS (ushorts): A buf b at b*16384 ([kh][256][32] f16, chunk^=((row>>1)&3));
//   BQ buf b at 32768+b*4096 (256 rows x 32B nibbles, XOR-swizzled
//   phys4 = s ^ (((s>>5)&7)<<2), staged via inverse source t^((t>>3)&7));
//   SL at 40960 ([64][256] f16 scales, staged once). 112 KB.
// Loads/iter = 10: P1{A11 x2, BQ1} P3{A00' x2} P4{BQ0'} P5{A01' x2} P7{A10' x2}.
// Waits: VW(5)@P1, VW(2)@P3, VW(4)@P7. FIFO-sim: entry [A01x2,A10x2];
//   P1 drains A01 (read P2-top); P3 drains A10,A11,BQ1 (read P4/P6-top);
//   P7 drains A00',BQ0' (read P8-top). Every read >= 1 barrier after its publish.
// WAR: P1:A11<-prevP7, P1:BQ1<-prevP6, P3:A00<-P1, P4:BQ0<-P2, P5:A01<-P3,
//   P7:A10<-P5 (all >=1 barrier). Prologue = exact steady entry state.
__global__ __launch_bounds__(512, 2) void gemm_bt(const unsigned short* __restrict__ A,
                                                  const unsigned char* __restrict__ WQ,
                                                  const unsigned short* __restrict__ ST,
                                                  float* __restrict__ C) {
  __shared__ __align__(16) unsigned short lds[57344];  // 112 KB

  const int NT  = OUT_F / BN;              // 43
  const int nwg = (M_ROWS / BM) * NT;      // 1376, %8==0
  const int cpx = nwg >> 3;
  const int bid = blockIdx.x;
  const int swz = (bid & 7) * cpx + (bid >> 3);
  const int mt  = swz / NT;
  const int nt  = swz - mt * NT;
  const int n0  = nt * BN;

  const int tid  = threadIdx.x;
  const int lane = tid & 63;
  const int wid  = tid >> 6;      // 8 waves: 2 (M) x 4 (N)
  const int wr   = wid >> 2;
  const int wc   = wid & 3;

  // ---- A staging (unchanged from R13) ----
  const int r_st = tid >> 2;
  const int lc   = (tid & 3) ^ ((tid >> 3) & 3);
  const unsigned short* gA = A + (size_t)(mt * BM + r_st) * IN_F + lc * 8;
  unsigned short* ldsw = lds + tid * 8;

#define STAGE_A(b, h, kk) do {                                              \
    unsigned short* d_ = ldsw + (b) * 16384 + (h) * 8192;                   \
    const unsigned short* s_ = gA + (kk) + (h) * 32;                        \
    gld16(s_, d_); gld16(s_ + (size_t)128 * IN_F, d_ + 4096);               \
  } while (0)

  // ---- BQ staging: dest chunk16 = tid (linear); logical chunk = tid ^ ((tid>>3)&7) ----
  const int bql = tid ^ ((tid >> 3) & 7);
  const unsigned char* gBQ = WQ + (size_t)(n0 + (bql >> 1)) * (IN_F / 2) + (bql & 1) * 16;
#define STAGE_BQ(b, tk) \
    gld16(gBQ + (size_t)(tk) * 32, lds + 32768 + (b) * 4096 + tid * 8)

  // ---- SL staging (prologue only) ----
#define STAGE_SL(c) do {                                                    \
    const int sl_ = (c) * 512 + tid;                                        \
    gld16(ST + (size_t)(sl_ >> 5) * OUT_F + n0 + (sl_ & 31) * 8,            \
          lds + 40960 + sl_ * 8);                                           \
  } while (0)

  // ---- fragment reads ----
  const int fr   = lane & 15;
  const int kq   = lane >> 4;
  const int coff = (kq ^ ((fr >> 1) & 3)) * 8;

  f16x8 afrA[4], afrB[4], bfrA[4], bfrB[4];
#define RD_A(dst, b, h, mq) do {                                            \
    const unsigned short* p_ = lds + (b) * 16384 + (h) * 8192 + coff;       \
    _Pragma("unroll") for (int mm = 0; mm < 4; ++mm)                        \
      dst[mm] = *reinterpret_cast<const f16x8*>(                            \
          p_ + (size_t)(wr * 128 + (mq) * 64 + mm * 16 + fr) * 32);         \
  } while (0)

  // packed-B read (swizzled) + cheap dequant (interleaved nibbles).
#define DEQ_B(dst, bbuf, kh, g) do {                                        \
    _Pragma("unroll") for (int nn = 0; nn < 4; ++nn) {                      \
      const int o_ = wc * 64 + nn * 16 + fr;                                \
      const int s4_ = o_ * 8 + (kh) * 4 + kq;                               \
      const int ph_ = s4_ ^ (((s4_ >> 5) & 7) << 2);                        \
      const unsigned int w4 = *reinterpret_cast<const unsigned int*>(       \
          lds + 32768 + (bbuf) * 4096 + ph_ * 2);                           \
      const _Float16 s_  = *reinterpret_cast<const _Float16*>(              \
          lds + 40960 + (g) * 256 + o_);                                    \
      const _Float16 c1_ = s_ * (_Float16)(-1024.0f);  /* exact */          \
      const _Float16 c8_ = s_ * (_Float16)(-8.0f);     /* exact */          \
      f16x2 s2; s2[0] = s_;  s2[1] = s_;                                    \
      f16x2 c1; c1[0] = c1_; c1[1] = c1_;                                   \
      f16x2 c8; c8[0] = c8_; c8[1] = c8_;                                   \
      uint4v rr;                                                            \
      _Pragma("unroll") for (int p = 0; p < 4; ++p) {                       \
        const unsigned int m_ = ((w4 >> (4 * p)) & 0x000F000Fu)             \
                              | 0x64006400u;                                \
        f16x2 v_ = __builtin_bit_cast(f16x2, m_);                           \
        v_ = __builtin_elementwise_fma(v_, s2, c1);                         \
        v_ = v_ + c8;                                                       \
        rr[p] = __builtin_bit_cast(unsigned int, v_);                       \
      }                                                                     \
      dst[nn] = __builtin_bit_cast(f16x8, rr);                              \
    }                                                                       \
  } while (0)

  f32x4 acc[8][4] = {};
#define MFMA16(mq, aset, bset) do {                                         \
    __builtin_amdgcn_s_setprio(1);                                          \
    _Pragma("unroll") for (int mm = 0; mm < 4; ++mm)                        \
      _Pragma("unroll") for (int nn = 0; nn < 4; ++nn)                      \
        acc[(mq)*4+mm][nn] = __builtin_amdgcn_mfma_f32_16x16x32_f16(        \
            aset[mm], bset[nn], acc[(mq)*4+mm][nn], 0, 0, 0);               \
    __builtin_amdgcn_s_setprio(0);                                          \
  } while (0)

#define VW(n) asm volatile("s_waitcnt vmcnt(" #n ")" ::: "memory")

  // ---- prologue: 11 loads; VW(4) drains SLx4+A00x2+BQ0; outstanding [A01x2,A10x2];
  //      pre-read MFMA(P1) operands ----
  STAGE_SL(0); STAGE_SL(1); STAGE_SL(2); STAGE_SL(3);
  STAGE_A(0, 0, 0);
  STAGE_BQ(0, 0);
  STAGE_A(0, 1, 0);
  STAGE_A(1, 0, BK);
  VW(4);
  BAR();
  RD_A(afrA, 0, 0, 0);
  DEQ_B(bfrA, 0, 0, 0);

  for (int it = 0; it < NTILE_K / 2; ++it) {
    const int ta  = 2 * it;
    const int tb  = 2 * it + 1;
    const int tna = (2 * it + 2) & (NTILE_K - 1);
    const int tnb = (2 * it + 3) & (NTILE_K - 1);

    // P1: stage A11(tb)+BQ1(tb) ; RD->P2 A(0,0,m4-7) ; VW(5) ; MFMA(afrA,bfrA)
    STAGE_A(1, 1, tb * BK); STAGE_BQ(1, tb);
    RD_A(afrB, 0, 0, 1);
    VW(5);
    BAR(); MFMA16(0, afrA, bfrA);
    // P2: RD->P3 A(0,1,m0-3) + DEQ B(0,kh1,ta) ; MFMA(afrB,bfrA)
    RD_A(afrA, 0, 1, 0); DEQ_B(bfrB, 0, 1, ta);
    BAR(); MFMA16(1, afrB, bfrA);
    // P3: stage A00'(tna) ; RD->P4 A(0,1,m4-7) ; VW(2) ; MFMA(afrA,bfrB)
    STAGE_A(0, 0, tna * BK);
    RD_A(afrB, 0, 1, 1);
    VW(2);
    BAR(); MFMA16(0, afrA, bfrB);
    // P4: stage BQ0'(tna) ; RD->P5 A(1,0,m0-3) + DEQ B(1,kh0,tb) ; MFMA(afrB,bfrB)
    STAGE_BQ(0, tna);
    RD_A(afrA, 1, 0, 0); DEQ_B(bfrA, 1, 0, tb);
    BAR(); MFMA16(1, afrB, bfrB);
    // P5: stage A01'(tna) ; RD->P6 A(1,0,m4-7) ; MFMA(afrA,bfrA)
    STAGE_A(0, 1, tna * BK);
    RD_A(afrB, 1, 0, 1);
    BAR(); MFMA16(0, afrA, bfrA);
    // P6: RD->P7 A(1,1,m0-3) + DEQ B(1,kh1,tb) ; MFMA(afrB,bfrA)
    RD_A(afrA, 1, 1, 0); DEQ_B(bfrB, 1, 1, tb);
    BAR(); MFMA16(1, afrB, bfrA);
    // P7: stage A10'(tnb) ; RD->P8 A(1,1,m4-7) ; VW(4) ; MFMA(afrA,bfrB)
    STAGE_A(1, 0, tnb * BK);
    RD_A(afrB, 1, 1, 1);
    VW(4);
    BAR(); MFMA16(0, afrA, bfrB);
    // P8: RD->next-P1 A(0,0,m0-3)' + DEQ B(0,kh0,tna)' ; MFMA(afrB,bfrB)
    RD_A(afrA, 0, 0, 0); DEQ_B(bfrA, 0, 0, tna);
    BAR(); MFMA16(1, afrB, bfrB);
  }

  asm volatile("s_waitcnt vmcnt(0)" ::: "memory");  // drain tail stages

  // ---- epilogue: plain stores ----
  const int col  = n0 + wc * 64 + fr;
  const int row0 = mt * BM + wr * 128 + (lane >> 4) * 4;
#pragma unroll
  for (int m = 0; m < 8; ++m) {
#pragma unroll
    for (int n = 0; n < 4; ++n) {
      float* cp = C + (size_t)(row0 + m * 16) * OUT_F + (col + n * 16);
#pragma unroll
      for (int r = 0; r < 4; ++r) cp[(size_t)r * OUT_F] = acc[m][n][r];
    }
  }
}

extern "C" void kernel_launch(void* const* d_in, const int* in_sizes, int n_in,
                              void* d_out, int out_size, void* d_ws, size_t ws_size,
                              hipStream_t stream) {
  const float* x = (const float*)d_in[0];
  const int*   w = (const int*)d_in[1];
  const float* s = (const float*)d_in[2];
  float*     out = (float*)d_out;

  // d_ws: xb f16 [8192][4096] (64 MB) | wq packed u32 (21.5 MB) | st f16 (1.35 MB)
  unsigned short* xb = (unsigned short*)d_ws;
  unsigned char*  wq = (unsigned char*)d_ws + (size_t)M_ROWS * IN_F * 2;
  unsigned short* st = (unsigned short*)(wq + (size_t)OUT_F * (IN_F / 2));

  pack_w<<<dim3(2048), dim3(256), 0, stream>>>(w, (unsigned int*)wq);
  scale_t<<<dim3(43, 64), dim3(256), 0, stream>>>(s, st);
  cvt_x<<<dim3(2048), dim3(256), 0, stream>>>(x, xb);
  gemm_bt<<<dim3((M_ROWS / BM) * (OUT_F / BN)), dim3(512), 0, stream>>>(xb, wq, st, out);
}